// Round 12
// baseline (184.526 us; speedup 1.0000x reference)
//
#include <hip/hip_runtime.h>
#include <hip/hip_bf16.h>
#include <math.h>

#define N_PIX 3136
#define NPAD 3200
#define CDIM 432
#define NHEADS 8
#define HD 54
#define KK 49
#define C2 392

typedef __attribute__((ext_vector_type(8))) short bf16x8;
typedef __attribute__((ext_vector_type(4))) float f32x4;
typedef __attribute__((ext_vector_type(8))) unsigned short ushort8;
typedef __attribute__((ext_vector_type(2))) unsigned short ushort2v;

__device__ __forceinline__ void gload_lds16(const void* g, void* l) {
    __builtin_amdgcn_global_load_lds(
        (const __attribute__((address_space(1))) void*)g,
        (__attribute__((address_space(3))) void*)l, 16, 0, 0);
}

__device__ __forceinline__ unsigned short f2bf(float f) {
    __hip_bfloat16 b = __float2bfloat16(f);
    unsigned short u;
    __builtin_memcpy(&u, &b, 2);
    return u;
}

// storage permutation: element (r,k) of a row-major (.,Kp) bf16 matrix lives at
// chunk position ((k>>3)&7) ^ (r&7) within its 64-element k-block -> linear
// global_load_lds lands an XOR-swizzled LDS tile (conflict-free ds_read_b128).
__device__ __forceinline__ size_t perm_off(int r, int k, int Kp) {
    int p = ((k >> 3) & 7) ^ (r & 7);
    return (size_t)r * Kp + ((k >> 6) << 6) + (p << 3) + (k & 7);
}

__device__ __forceinline__ void convert_body(
    const float* __restrict__ src, __hip_bfloat16* __restrict__ dst,
    int Mlog, int Mpad, int Klog, int Kp, int id)
{
    int chunks = Kp >> 3;
    if (id >= Mpad * chunks) return;
    int r = id / chunks, cb = id % chunks;
    int k0 = cb << 3;
    __hip_bfloat16 vv[8];
    #pragma unroll
    for (int e = 0; e < 8; e++) {
        int k = k0 + e;
        float f = (r < Mlog && k < Klog) ? src[(size_t)r * Klog + k] : 0.f;
        vv[e] = __float2bfloat16(f);
    }
    int p = (cb & 7) ^ (r & 7);
    __hip_bfloat16* d = dst + (size_t)r * Kp + ((cb >> 3) << 6) + (p << 3);
    *(ushort8*)d = *(const ushort8*)vv;
}

// merged preprocessing: ghost transpose + 4 bf16 permuted conversions +
// zero of qb16/kb16 pad channels 54..63 (the only bytes MFMA needs zeroed)
__global__ __launch_bounds__(256) void prep_kernel(
    const float* __restrict__ x, const float* __restrict__ qkv_w,
    const float* __restrict__ conv2_w, const float* __restrict__ proj2_w,
    const float* __restrict__ ghost,
    __hip_bfloat16* __restrict__ xb, __hip_bfloat16* __restrict__ qkvwb,
    __hip_bfloat16* __restrict__ c2wb, __hip_bfloat16* __restrict__ p2wb,
    float* __restrict__ ghostT, __hip_bfloat16* __restrict__ qkbase)
{
    int b = blockIdx.x;
    if (b < 83) {
        int id = b * 256 + threadIdx.x;
        if (id < CDIM * KK) {
            int cc = id / KK, t = id % KK;
            ghostT[t * CDIM + cc] = ghost[id];
        }
    } else if (b < 769) {
        convert_body(x, xb, 3136, 3136, 432, 448, (b - 83) * 256 + threadIdx.x);
    } else if (b < 1063) {
        convert_body(qkv_w, qkvwb, 1296, 1344, 432, 448, (b - 769) * 256 + threadIdx.x);
    } else if (b < 1161) {
        convert_body(conv2_w, c2wb, 392, 448, 432, 448, (b - 1063) * 256 + threadIdx.x);
    } else if (b < 1357) {
        convert_body(proj2_w, p2wb, 432, 448, 864, 896, (b - 1161) * 256 + threadIdx.x);
    } else {
        // zero ch 54..63 of qb16 and kb16: 2 * 8 * 3200 rows
        int id = (b - 1357) * 256 + threadIdx.x;
        if (id < 2 * 8 * NPAD) {
            __hip_bfloat16* p = qkbase + (size_t)id * 64;
            *(ushort2v*)((unsigned short*)p + 54) = (ushort2v)0;
            *(ushort8*)((unsigned short*)p + 56) = (ushort8)0;
        }
    }
}

// ---------------------------------------------------------------------------
// bf16 MFMA GEMM v2: 128x128 tile, BK=64, 4 waves each owning a 64x64
// quadrant (acc[4][4] of 16x16x32). Same perm/XOR LDS scheme as before.
// mode 0: qkv epilogue -> q fp32(*scale)+qb16, k fp32+kb16, v->vb16
// (bf16 copies head-major [h][pix][64]). mode 1: plain fp32 -> O0.
// ---------------------------------------------------------------------------
__global__ __launch_bounds__(256) void gemm_mfma2(
    const __hip_bfloat16* __restrict__ A, const __hip_bfloat16* __restrict__ B,
    const float* __restrict__ bias,
    float* __restrict__ O0, float* __restrict__ O1,
    __hip_bfloat16* __restrict__ VB,
    __hip_bfloat16* __restrict__ QB, __hip_bfloat16* __restrict__ KB,
    int Mlog, int Nlog, int Kp, int mode, float qscale, int ldO)
{
    __shared__ __hip_bfloat16 lA[128 * 64];
    __shared__ __hip_bfloat16 lB[128 * 64];
    const int tid = threadIdx.x;
    const int w = tid >> 6, lane = tid & 63;
    const int row0 = blockIdx.y * 128, col0 = blockIdx.x * 128;
    const int wr = (w >> 1) * 64, wc = (w & 1) * 64;
    const int srow = lane >> 3, schk = lane & 7;
    f32x4 acc[4][4] = {};

    for (int k0 = 0; k0 < Kp; k0 += 64) {
        #pragma unroll
        for (int t = 0; t < 4; t++) {
            int lid = w * 4 + t;
            const __hip_bfloat16* ga =
                A + (size_t)(row0 + lid * 8 + srow) * Kp + k0 + schk * 8;
            gload_lds16(ga, &lA[lid * 8 * 64]);
            const __hip_bfloat16* gb =
                B + (size_t)(col0 + lid * 8 + srow) * Kp + k0 + schk * 8;
            gload_lds16(gb, &lB[lid * 8 * 64]);
        }
        __syncthreads();
        #pragma unroll
        for (int ks = 0; ks < 2; ks++) {
            bf16x8 af[4], bfr[4];
            int c = ks * 4 + (lane >> 4);
            #pragma unroll
            for (int mi = 0; mi < 4; mi++) {
                int ra = wr + mi * 16 + (lane & 15);
                af[mi] = *(const bf16x8*)&lA[ra * 64 + ((c ^ (ra & 7)) << 3)];
                int rb = wc + mi * 16 + (lane & 15);
                bfr[mi] = *(const bf16x8*)&lB[rb * 64 + ((c ^ (rb & 7)) << 3)];
            }
            #pragma unroll
            for (int mi = 0; mi < 4; mi++)
                #pragma unroll
                for (int ni = 0; ni < 4; ni++)
                    acc[mi][ni] = __builtin_amdgcn_mfma_f32_16x16x32_bf16(
                        af[mi], bfr[ni], acc[mi][ni], 0, 0, 0);
        }
        __syncthreads();
    }

    #pragma unroll
    for (int mi = 0; mi < 4; mi++) {
        #pragma unroll
        for (int ni = 0; ni < 4; ni++) {
            #pragma unroll
            for (int rr = 0; rr < 4; rr++) {
                int r = row0 + wr + mi * 16 + (lane >> 4) * 4 + rr;
                int cc = col0 + wc + ni * 16 + (lane & 15);
                if (r >= Mlog || cc >= Nlog) continue;
                float val = acc[mi][ni][rr] + bias[cc];
                if (mode == 0) {
                    int s = cc / CDIM, cch = cc - s * CDIM;
                    int hh = cch / HD, dd = cch - hh * HD;
                    if (s == 0) {
                        float qv = val * qscale;
                        O0[(size_t)r * CDIM + cch] = qv;
                        QB[((size_t)hh * NPAD + r) * 64 + dd] = __float2bfloat16(qv);
                    } else if (s == 1) {
                        O1[(size_t)r * CDIM + cch] = val;
                        KB[((size_t)hh * NPAD + r) * 64 + dd] = __float2bfloat16(val);
                    } else {
                        VB[((size_t)hh * N_PIX + r) * 64 + dd] = __float2bfloat16(val);
                    }
                } else {
                    O0[(size_t)r * ldO + cc] = val;
                }
            }
        }
    }
}

// ---------------------------------------------------------------------------
// attn via MFMA: block = (head, row i). S = q_row(56x64) @ k_nbr(392x64)^T;
// fragments loaded directly from global bf16 head-major buffers; logits fp32
// in LDS; phase 2 = rpb add + 49-lane shfl softmax.
// ---------------------------------------------------------------------------
__global__ __launch_bounds__(256) void attn_mfma(
    const __hip_bfloat16* __restrict__ qb, const __hip_bfloat16* __restrict__ kb,
    const float* __restrict__ rpb, float* __restrict__ attn)
{
    __shared__ float Sl[16][404];
    __shared__ float rpb_l[169];
    int bid = blockIdx.x;
    int nb = (bid & 7) * 56 + (bid >> 3);         // 448 = 8 * 56, bijective
    int h = nb / 56, i = nb - (nb / 56) * 56;
    int tid = threadIdx.x;
    int w = tid >> 6, lane = tid & 63;
    int l15 = lane & 15, l4 = lane >> 4;
    int ni = min(max(i - 3, 0), 49);

    for (int f = tid; f < 169; f += 256) rpb_l[f] = rpb[h * 169 + f];
    __syncthreads();

    const __hip_bfloat16* qrow = qb + ((size_t)h * NPAD + i * 56) * 64;
    const __hip_bfloat16* kwin = kb + ((size_t)h * NPAD + ni * 56) * 64;

    for (int rt = 0; rt < 4; rt++) {
        bf16x8 af0 = *(const bf16x8*)(qrow + (size_t)(rt * 16 + l15) * 64 + l4 * 8);
        bf16x8 af1 = *(const bf16x8*)(qrow + (size_t)(rt * 16 + l15) * 64 + 32 + l4 * 8);
        for (int ct = w; ct < 25; ct += 4) {
            bf16x8 b0 = *(const bf16x8*)(kwin + (size_t)(ct * 16 + l15) * 64 + l4 * 8);
            bf16x8 b1 = *(const bf16x8*)(kwin + (size_t)(ct * 16 + l15) * 64 + 32 + l4 * 8);
            f32x4 acc = {};
            acc = __builtin_amdgcn_mfma_f32_16x16x32_bf16(af0, b0, acc, 0, 0, 0);
            acc = __builtin_amdgcn_mfma_f32_16x16x32_bf16(af1, b1, acc, 0, 0, 0);
            int col = ct * 16 + l15;
            #pragma unroll
            for (int r = 0; r < 4; r++)
                Sl[l4 * 4 + r][col] = acc[r];
        }
        __syncthreads();
        #pragma unroll
        for (int pp = 0; pp < 4; pp++) {
            int j = rt * 16 + w * 4 + pp;
            if (j < 56) {
                int n = i * 56 + j;
                int nj = min(max(j - 3, 0), 49);
                int t = lane;
                float logit = -1e30f;
                if (t < KK) {
                    int u = t / 7, v = t - (t / 7) * 7;
                    int col = u * 56 + nj + v;
                    int ri = 6 - (i - ni) + u;
                    int rj = 6 - (j - nj) + v;
                    logit = Sl[j - rt * 16][col] + rpb_l[ri * 13 + rj];
                }
                float m = logit;
                #pragma unroll
                for (int off = 32; off; off >>= 1) m = fmaxf(m, __shfl_xor(m, off));
                float e = (t < KK) ? expf(logit - m) : 0.f;
                float ssum = e;
                #pragma unroll
                for (int off = 32; off; off >>= 1) ssum += __shfl_xor(ssum, off);
                if (t < KK) attn[(size_t)n * C2 + h * KK + t] = e / ssum;
            }
        }
        __syncthreads();
    }
}

// ---------------------------------------------------------------------------
// Grouped 7x7 conv + GELU; had = q*k*scale fused into staging (float4 loads).
// ---------------------------------------------------------------------------
#define TH 4
__global__ __launch_bounds__(256) void conv1_gelu_v2(
    const float* __restrict__ q, const float* __restrict__ k,
    const float* __restrict__ w, const float* __restrict__ b,
    __hip_bfloat16* __restrict__ out, float scale)
{
    int g = blockIdx.x % 54;
    int rt = blockIdx.x / 54;      // 0..13
    int r0 = rt * TH;
    int tid = threadIdx.x;
    int waveid = tid >> 6, lane = tid & 63;
    int ic = lane >> 3, oc = lane & 7;

    __shared__ float smem[10][8][68];

    float* sflat = &smem[0][0][0];
    for (int i = tid; i < 10 * 8 * 68; i += 256) sflat[i] = 0.f;

    float wreg[49];
    {
        const float* wp = w + ((size_t)(g * 8 + oc) * 8 + ic) * 49;
        #pragma unroll
        for (int t = 0; t < 49; t++) wreg[t] = wp[t];
    }
    __syncthreads();

    // stage: f -> (row rr, pixel pj, channel-half); float4 q/k loads
    for (int f = tid; f < 10 * 56 * 2; f += 256) {
        int rr = f / 112, rem = f - rr * 112;
        int pj = rem >> 1, half = rem & 1;
        int pi = r0 - 3 + rr;
        if (pi >= 0 && pi < 56) {
            size_t off = (size_t)(pi * 56 + pj) * CDIM + g * 8 + half * 4;
            float4 qv = *(const float4*)(q + off);
            float4 kv = *(const float4*)(k + off);
            int c0 = half * 4;
            smem[rr][c0 + 0][pj + 3] = qv.x * kv.x * scale;
            smem[rr][c0 + 1][pj + 3] = qv.y * kv.y * scale;
            smem[rr][c0 + 2][pj + 3] = qv.z * kv.z * scale;
            smem[rr][c0 + 3][pj + 3] = qv.w * kv.w * scale;
        }
    }
    __syncthreads();

    int r = r0 + waveid;
    float bias_o = b[g * 8 + oc];
    for (int j0 = 0; j0 < 56; j0 += 4) {
        float acc0 = 0.f, acc1 = 0.f, acc2 = 0.f, acc3 = 0.f;
        #pragma unroll
        for (int u = 0; u < 7; u++) {
            const float* rp = &smem[waveid + u][ic][j0];
            float4 c0 = *(const float4*)(rp);
            float4 c1 = *(const float4*)(rp + 4);
            float4 c2 = *(const float4*)(rp + 8);
            float col[12] = {c0.x, c0.y, c0.z, c0.w,
                             c1.x, c1.y, c1.z, c1.w,
                             c2.x, c2.y, c2.z, c2.w};
            #pragma unroll
            for (int v = 0; v < 7; v++) {
                float wv = wreg[u * 7 + v];
                acc0 += wv * col[v + 0];
                acc1 += wv * col[v + 1];
                acc2 += wv * col[v + 2];
                acc3 += wv * col[v + 3];
            }
        }
        float accs[4] = {acc0, acc1, acc2, acc3};
        #pragma unroll
        for (int jj = 0; jj < 4; jj++) {
            float s = accs[jj];
            s += __shfl_xor(s, 8);
            s += __shfl_xor(s, 16);
            s += __shfl_xor(s, 32);
            accs[jj] = s;
        }
        if (ic == 0) {
            #pragma unroll
            for (int jj = 0; jj < 4; jj++) {
                float a = accs[jj] + bias_o;
                float gl = 0.5f * a * (1.0f + erff(a * 0.70710678118654752f));
                int n = r * 56 + j0 + jj;
                int kch = g * 8 + oc;
                out[perm_off(n, kch, 448)] = __float2bfloat16(gl);
            }
        }
    }
}

// ---------------------------------------------------------------------------
// softmax_pack: per pixel: softmax over 392 channels of h2, then pack per
// (head, tap): hi16 = bf16(attn), lo16 = bf16(attn + hat) into pk[n][h][52].
// ---------------------------------------------------------------------------
__global__ __launch_bounds__(128) void softmax_pack(
    const float* __restrict__ h2, const float* __restrict__ attn,
    unsigned* __restrict__ pk)
{
    __shared__ float red[128];
    int n = blockIdx.x, tid = threadIdx.x;
    const float* row = h2 + (size_t)n * C2;
    float m = -1e30f;
    float rv[4];
    #pragma unroll
    for (int idx = 0; idx < 4; idx++) {
        int c = tid + idx * 128;
        rv[idx] = (c < C2) ? row[c] : -1e30f;
        m = fmaxf(m, rv[idx]);
    }
    red[tid] = m; __syncthreads();
    for (int s = 64; s; s >>= 1) {
        if (tid < s) red[tid] = fmaxf(red[tid], red[tid + s]);
        __syncthreads();
    }
    m = red[0]; __syncthreads();
    float loc = 0.f;
    #pragma unroll
    for (int idx = 0; idx < 4; idx++) {
        int c = tid + idx * 128;
        if (c < C2) { rv[idx] = expf(rv[idx] - m); loc += rv[idx]; }
    }
    red[tid] = loc; __syncthreads();
    for (int s = 64; s; s >>= 1) {
        if (tid < s) red[tid] += red[tid + s];
        __syncthreads();
    }
    float inv = 1.0f / red[0];
    #pragma unroll
    for (int idx = 0; idx < 4; idx++) {
        int c = tid + idx * 128;
        if (c < C2) {
            float hval = rv[idx] * inv;
            float a = attn[(size_t)n * C2 + c];
            int hh = c / KK, t = c - hh * KK;
            unsigned word = ((unsigned)f2bf(a) << 16) | (unsigned)f2bf(a + hval);
            pk[((size_t)n * 8 + hh) * 52 + t] = word;
        }
    }
}

// ---------------------------------------------------------------------------
// combine_int: one wave per interior pixel; pk wave-uniform weights (zero
// shfl); S_ah/S_a/S_g accumulators; ghost head-slice in LDS; bf16 v.
// ---------------------------------------------------------------------------
__global__ __launch_bounds__(256) void combine_int(
    const __hip_bfloat16* __restrict__ vb, const unsigned* __restrict__ pk,
    const float* __restrict__ ghostT, __hip_bfloat16* __restrict__ comb)
{
    __shared__ float gs[KK * HD];
    int bid = blockIdx.x;
    int nb = (bid & 7) * 625 + (bid >> 3);        // 5000 = 8 * 625
    int h = (nb * 4) / 2500;                       // uniform per block
    for (int f = threadIdx.x; f < KK * HD; f += 256) {
        int t = f / HD, dd = f - t * HD;
        gs[f] = ghostT[t * CDIM + h * HD + dd];
    }
    __syncthreads();

    int task = nb * 4 + (threadIdx.x >> 6);
    task = __builtin_amdgcn_readfirstlane(task);
    int lane = threadIdx.x & 63;
    int rem = task - h * 2500;
    int i = 3 + rem / 50;
    int j = 3 + (rem - (rem / 50) * 50);
    int n = i * 56 + j;
    int d = (lane < HD) ? lane : (HD - 1);
    bool lo = (d < 27);

    const unsigned* pkrow = pk + ((size_t)n * 8 + h) * 52;
    const __hip_bfloat16* vwin =
        vb + ((size_t)h * N_PIX + (i - 3) * 56 + (j - 3)) * 64 + d;

    float S_ah = 0.f, S_a = 0.f, S_g = 0.f;
    #pragma unroll
    for (int u = 0; u < 7; u++) {
        float vrow[7];
        #pragma unroll
        for (int vv = 0; vv < 7; vv++)
            vrow[vv] = __bfloat162float(vwin[(u * 56 + vv) * 64]);
        #pragma unroll
        for (int vv = 0; vv < 7; vv++) {
            const int t = u * 7 + vv;
            unsigned s = pkrow[t];
            float a  = __uint_as_float(s & 0xFFFF0000u);
            float ah = __uint_as_float(s << 16);
            float gt = gs[t * HD + d];
            S_ah += ah * vrow[vv];
            S_a  += a  * vrow[vv];
            S_g  += gt * vrow[vv];
        }
    }
    if (lane < HD) {
        float av = S_ah;
        float Sh = S_ah - S_a;
        float elsa = S_g + (lo ? S_a : Sh);
        comb[perm_off(n, h * 108 + d, 896)]      = __float2bfloat16(av);
        comb[perm_off(n, h * 108 + 54 + d, 896)] = __float2bfloat16(elsa);
    }
}

// ---------------------------------------------------------------------------
// combine_bdr: 636 border pixels x 8 heads, one wave per pixel.
// ---------------------------------------------------------------------------
__global__ __launch_bounds__(256) void combine_bdr(
    const __hip_bfloat16* __restrict__ vb, const unsigned* __restrict__ pk,
    const float* __restrict__ ghostT, __hip_bfloat16* __restrict__ comb)
{
    __shared__ float gs[KK * HD];
    int bid = blockIdx.x;
    int nb = (bid & 7) * 159 + (bid >> 3);        // 1272 = 8 * 159
    int h = (nb * 4) / 636;                        // uniform per block
    for (int f = threadIdx.x; f < KK * HD; f += 256) {
        int t = f / HD, dd = f - t * HD;
        gs[f] = ghostT[t * CDIM + h * HD + dd];
    }
    __syncthreads();

    int task = nb * 4 + (threadIdx.x >> 6);
    task = __builtin_amdgcn_readfirstlane(task);
    int lane = threadIdx.x & 63;
    int idx = task - h * 636;
    int i, j;
    if (idx < 336) {
        int r = idx / 56;
        i = (r < 3) ? r : 50 + r;                 // 0,1,2,53,54,55
        j = idx - r * 56;
    } else {
        int idx2 = idx - 336;                     // 0..299
        i = 3 + idx2 / 6;
        int jj = idx2 - (idx2 / 6) * 6;
        j = (jj < 3) ? jj : 50 + jj;              // 0,1,2, 53,54,55
    }
    int n = i * 56 + j;
    int d = (lane < HD) ? lane : (HD - 1);
    bool lo = (d < 27);

    const unsigned* pkrow = pk + ((size_t)n * 8 + h) * 52;
    int ni = min(max(i - 3, 0), 49), nj = min(max(j - 3, 0), 49);
    const __hip_bfloat16* vhead = vb + (size_t)h * N_PIX * 64 + d;
    const __hip_bfloat16* vbc = vhead + (size_t)(ni * 56 + nj) * 64;

    float S_ahc = 0.f, S_ap = 0.f, S_ahp = 0.f, S_gp = 0.f;
    #pragma unroll
    for (int t = 0; t < KK; t++) {
        const int u = t / 7, vv = t % 7;
        unsigned s = pkrow[t];
        float a  = __uint_as_float(s & 0xFFFF0000u);
        float ah = __uint_as_float(s << 16);
        float vc = __bfloat162float(vbc[(u * 56 + vv) * 64]);
        S_ahc += ah * vc;
        int pi = i + u - 3, pj = j + vv - 3;
        if (pi >= 0 && pi < 56 && pj >= 0 && pj < 56) {
            float vp = __bfloat162float(vhead[(size_t)(pi * 56 + pj) * 64]);
            float gt = gs[t * HD + d];
            S_ahp += ah * vp; S_ap += a * vp; S_gp += gt * vp;
        }
    }
    if (lane < HD) {
        float av = S_ahc;
        float Shp = S_ahp - S_ap;
        float elsa = S_gp + (lo ? S_ap : Shp);
        comb[perm_off(n, h * 108 + d, 896)]      = __float2bfloat16(av);
        comb[perm_off(n, h * 108 + 54 + d, 896)] = __float2bfloat16(elsa);
    }
}

extern "C" void kernel_launch(void* const* d_in, const int* in_sizes, int n_in,
                              void* d_out, int out_size, void* d_ws, size_t ws_size,
                              hipStream_t stream)
{
    const float* x       = (const float*)d_in[0];
    const float* qkv_w   = (const float*)d_in[1];
    const float* qkv_b   = (const float*)d_in[2];
    const float* rpb     = (const float*)d_in[3];
    const float* conv1_w = (const float*)d_in[4];
    const float* conv1_b = (const float*)d_in[5];
    const float* conv2_w = (const float*)d_in[6];
    const float* conv2_b = (const float*)d_in[7];
    const float* ghost   = (const float*)d_in[8];
    const float* proj2_w = (const float*)d_in[9];
    const float* proj2_b = (const float*)d_in[10];
    float* out = (float*)d_out;

    float* ws = (float*)d_ws;
    const size_t NC = (size_t)N_PIX * CDIM;       // 1354752
    const size_t NA = (size_t)N_PIX * C2;         // 1229312
    float* q      = ws;
    float* k      = q + NC;
    float* attn   = k + NC;
    float* hat    = attn + NA;
    float* ghostT = hat + NA;                     // 21168
    unsigned* pk  = (unsigned*)(ghostT + 21168);  // 3136*8*52 = 1304576
    __hip_bfloat16* bfbase = (__hip_bfloat16*)(pk + 1304576);
    __hip_bfloat16* xb     = bfbase;                    // 3136 x 448
    __hip_bfloat16* qkvwb  = xb    + (size_t)3136 * 448;
    __hip_bfloat16* c2wb   = qkvwb + (size_t)1344 * 448;
    __hip_bfloat16* p2wb   = c2wb  + (size_t)448 * 448;
    __hip_bfloat16* hb     = p2wb  + (size_t)448 * 896; // 3136 x 448
    __hip_bfloat16* cb     = hb    + (size_t)3136 * 448;// 3136 x 896
    __hip_bfloat16* vb16   = cb    + (size_t)3136 * 896;// 8 x 3136 x 64
    __hip_bfloat16* qb16   = vb16  + (size_t)8 * N_PIX * 64; // 8 x 3200 x 64
    __hip_bfloat16* kb16   = qb16  + (size_t)8 * NPAD * 64;  // 8 x 3200 x 64

    const float scale = 0.13608276348795434f;     // 54^-0.5

    prep_kernel<<<1557, 256, 0, stream>>>(
        x, qkv_w, conv2_w, proj2_w, ghost, xb, qkvwb, c2wb, p2wb, ghostT, qb16);

    // qkv = x @ qkv_w^T + b  -> q fp32+qb16, k fp32+kb16, v bf16 head-major
    gemm_mfma2<<<dim3(11, 25), 256, 0, stream>>>(
        xb, qkvwb, qkv_b, q, k, vb16, qb16, kb16, 3136, 1296, 448, 0, scale, 0);

    attn_mfma<<<448, 256, 0, stream>>>(qb16, kb16, rpb, attn);

    conv1_gelu_v2<<<54 * 14, 256, 0, stream>>>(q, k, conv1_w, conv1_b, hb, scale);

    gemm_mfma2<<<dim3(4, 25), 256, 0, stream>>>(
        hb, c2wb, conv2_b, hat, nullptr, nullptr, nullptr, nullptr,
        3136, 392, 448, 1, 1.f, 392);

    softmax_pack<<<N_PIX, 128, 0, stream>>>(hat, attn, pk);

    combine_int<<<5000, 256, 0, stream>>>(vb16, pk, ghostT, cb);
    combine_bdr<<<1272, 256, 0, stream>>>(vb16, pk, ghostT, cb);

    gemm_mfma2<<<dim3(4, 25), 256, 0, stream>>>(
        cb, p2wb, proj2_b, out, nullptr, nullptr, nullptr, nullptr,
        3136, 432, 896, 1, 1.f, 432);
}

// Round 13
// 126.031 us; speedup vs baseline: 1.4641x; 1.4641x over previous
//
#include <hip/hip_runtime.h>
#include <hip/hip_bf16.h>
#include <math.h>

#define N_PIX 3136
#define NPAD 3200
#define CDIM 432
#define NHEADS 8
#define HD 54
#define KK 49
#define C2 392

typedef __attribute__((ext_vector_type(8))) short bf16x8;
typedef __attribute__((ext_vector_type(4))) float f32x4;
typedef __attribute__((ext_vector_type(8))) unsigned short ushort8;
typedef __attribute__((ext_vector_type(2))) unsigned short ushort2v;

__device__ __forceinline__ void gload_lds16(const void* g, void* l) {
    __builtin_amdgcn_global_load_lds(
        (const __attribute__((address_space(1))) void*)g,
        (__attribute__((address_space(3))) void*)l, 16, 0, 0);
}

__device__ __forceinline__ unsigned short f2bf(float f) {
    __hip_bfloat16 b = __float2bfloat16(f);
    unsigned short u;
    __builtin_memcpy(&u, &b, 2);
    return u;
}

// storage permutation: element (r,k) of a row-major (.,Kp) bf16 matrix lives at
// chunk position ((k>>3)&7) ^ (r&7) within its 64-element k-block -> linear
// global_load_lds lands an XOR-swizzled LDS tile (conflict-free ds_read_b128).
__device__ __forceinline__ size_t perm_off(int r, int k, int Kp) {
    int p = ((k >> 3) & 7) ^ (r & 7);
    return (size_t)r * Kp + ((k >> 6) << 6) + (p << 3) + (k & 7);
}

__device__ __forceinline__ void convert_body(
    const float* __restrict__ src, __hip_bfloat16* __restrict__ dst,
    int Mlog, int Mpad, int Klog, int Kp, int id)
{
    int chunks = Kp >> 3;
    if (id >= Mpad * chunks) return;
    int r = id / chunks, cb = id % chunks;
    int k0 = cb << 3;
    __hip_bfloat16 vv[8];
    #pragma unroll
    for (int e = 0; e < 8; e++) {
        int k = k0 + e;
        float f = (r < Mlog && k < Klog) ? src[(size_t)r * Klog + k] : 0.f;
        vv[e] = __float2bfloat16(f);
    }
    int p = (cb & 7) ^ (r & 7);
    __hip_bfloat16* d = dst + (size_t)r * Kp + ((cb >> 3) << 6) + (p << 3);
    *(ushort8*)d = *(const ushort8*)vv;
}

// merged preprocessing: ghost transpose + 4 bf16 permuted conversions +
// zero of qb16/kb16 pad channels 54..63 (the only bytes MFMA needs zeroed)
__global__ __launch_bounds__(256) void prep_kernel(
    const float* __restrict__ x, const float* __restrict__ qkv_w,
    const float* __restrict__ conv2_w, const float* __restrict__ proj2_w,
    const float* __restrict__ ghost,
    __hip_bfloat16* __restrict__ xb, __hip_bfloat16* __restrict__ qkvwb,
    __hip_bfloat16* __restrict__ c2wb, __hip_bfloat16* __restrict__ p2wb,
    float* __restrict__ ghostT, __hip_bfloat16* __restrict__ qkbase)
{
    int b = blockIdx.x;
    if (b < 83) {
        int id = b * 256 + threadIdx.x;
        if (id < CDIM * KK) {
            int cc = id / KK, t = id % KK;
            ghostT[t * CDIM + cc] = ghost[id];
        }
    } else if (b < 769) {
        convert_body(x, xb, 3136, 3136, 432, 448, (b - 83) * 256 + threadIdx.x);
    } else if (b < 1063) {
        convert_body(qkv_w, qkvwb, 1296, 1344, 432, 448, (b - 769) * 256 + threadIdx.x);
    } else if (b < 1161) {
        convert_body(conv2_w, c2wb, 392, 448, 432, 448, (b - 1063) * 256 + threadIdx.x);
    } else if (b < 1357) {
        convert_body(proj2_w, p2wb, 432, 448, 864, 896, (b - 1161) * 256 + threadIdx.x);
    } else {
        // zero ch 54..63 of qb16 and kb16: 2 * 8 * 3200 rows
        int id = (b - 1357) * 256 + threadIdx.x;
        if (id < 2 * 8 * NPAD) {
            __hip_bfloat16* p = qkbase + (size_t)id * 64;
            *(ushort2v*)((unsigned short*)p + 54) = (ushort2v)0;
            *(ushort8*)((unsigned short*)p + 56) = (ushort8)0;
        }
    }
}

// ---------------------------------------------------------------------------
// bf16 MFMA GEMM: out = A @ B^T + bias (64x64 tile, BK=64, 4 waves of 32x32)
// mode 0: qkv epilogue -> q fp32(*scale)+qb16, k fp32+kb16, v->vb16
// (bf16 copies head-major). mode 1: plain fp32 -> O0.  [R11-proven version]
// ---------------------------------------------------------------------------
__global__ __launch_bounds__(256) void gemm_mfma(
    const __hip_bfloat16* __restrict__ A, const __hip_bfloat16* __restrict__ B,
    const float* __restrict__ bias,
    float* __restrict__ O0, float* __restrict__ O1,
    __hip_bfloat16* __restrict__ VB,
    __hip_bfloat16* __restrict__ QB, __hip_bfloat16* __restrict__ KB,
    int Nlog, int Kp, int mode, float qscale, int ldO)
{
    __shared__ __hip_bfloat16 lA[64 * 64];
    __shared__ __hip_bfloat16 lB[64 * 64];
    const int tid = threadIdx.x;
    const int w = tid >> 6, lane = tid & 63;
    const int row0 = blockIdx.y * 64, col0 = blockIdx.x * 64;
    const int wr = (w >> 1) * 32, wc = (w & 1) * 32;
    const int srow = lane >> 3, schk = lane & 7;
    f32x4 acc[2][2] = {};

    for (int k0 = 0; k0 < Kp; k0 += 64) {
        #pragma unroll
        for (int t = 0; t < 2; t++) {
            int lid = w * 2 + t;
            const __hip_bfloat16* ga =
                A + (size_t)(row0 + lid * 8 + srow) * Kp + k0 + schk * 8;
            gload_lds16(ga, &lA[lid * 8 * 64]);
            const __hip_bfloat16* gb =
                B + (size_t)(col0 + lid * 8 + srow) * Kp + k0 + schk * 8;
            gload_lds16(gb, &lB[lid * 8 * 64]);
        }
        __syncthreads();
        #pragma unroll
        for (int ks = 0; ks < 2; ks++) {
            bf16x8 af[2], bfr[2];
            int c = ks * 4 + (lane >> 4);
            #pragma unroll
            for (int mi = 0; mi < 2; mi++) {
                int ra = wr + mi * 16 + (lane & 15);
                af[mi] = *(const bf16x8*)&lA[ra * 64 + ((c ^ (ra & 7)) << 3)];
                int rb = wc + mi * 16 + (lane & 15);
                bfr[mi] = *(const bf16x8*)&lB[rb * 64 + ((c ^ (rb & 7)) << 3)];
            }
            #pragma unroll
            for (int mi = 0; mi < 2; mi++)
                #pragma unroll
                for (int ni = 0; ni < 2; ni++)
                    acc[mi][ni] = __builtin_amdgcn_mfma_f32_16x16x32_bf16(
                        af[mi], bfr[ni], acc[mi][ni], 0, 0, 0);
        }
        __syncthreads();
    }

    #pragma unroll
    for (int mi = 0; mi < 2; mi++) {
        #pragma unroll
        for (int ni = 0; ni < 2; ni++) {
            #pragma unroll
            for (int rr = 0; rr < 4; rr++) {
                int r = row0 + wr + mi * 16 + (lane >> 4) * 4 + rr;
                int cc = col0 + wc + ni * 16 + (lane & 15);
                if (cc >= Nlog) continue;
                float val = acc[mi][ni][rr] + bias[cc];
                if (mode == 0) {
                    int s = cc / CDIM, cch = cc - s * CDIM;
                    int hh = cch / HD, dd = cch - hh * HD;
                    if (s == 0) {
                        float qv = val * qscale;
                        O0[(size_t)r * CDIM + cch] = qv;
                        QB[((size_t)hh * NPAD + r) * 64 + dd] = __float2bfloat16(qv);
                    } else if (s == 1) {
                        O1[(size_t)r * CDIM + cch] = val;
                        KB[((size_t)hh * NPAD + r) * 64 + dd] = __float2bfloat16(val);
                    } else {
                        VB[((size_t)hh * N_PIX + r) * 64 + dd] = __float2bfloat16(val);
                    }
                } else {
                    O0[(size_t)r * ldO + cc] = val;
                }
            }
        }
    }
}

// ---------------------------------------------------------------------------
// Fused attn_mfma + conv1_gelu: independent consumers of the qkv output,
// merged into ONE launch so they run concurrently across CUs.
// blocks [0,448): attn (head,row); blocks [448,1204): conv1 (group,row-tile).
// Shared LDS pool: max(attn 26532 B, conv1 21760 B).
// ---------------------------------------------------------------------------
#define TH 4
__global__ __launch_bounds__(256) void attn_conv1(
    const __hip_bfloat16* __restrict__ qb, const __hip_bfloat16* __restrict__ kb,
    const float* __restrict__ rpb, float* __restrict__ attn,
    const float* __restrict__ q, const float* __restrict__ k,
    const float* __restrict__ w, const float* __restrict__ b,
    __hip_bfloat16* __restrict__ out, float scale)
{
    __shared__ char sraw[26536];
    int tid = threadIdx.x;

    if (blockIdx.x < 448) {
        // ----- attn via MFMA -----
        float (*Sl)[404] = (float(*)[404])sraw;
        float* rpb_l = (float*)(sraw + 16 * 404 * 4);
        int bid = blockIdx.x;
        int nb = (bid & 7) * 56 + (bid >> 3);     // 448 = 8 * 56, bijective
        int h = nb / 56, i = nb - (nb / 56) * 56;
        int wv = tid >> 6, lane = tid & 63;
        int l15 = lane & 15, l4 = lane >> 4;
        int ni = min(max(i - 3, 0), 49);

        for (int f = tid; f < 169; f += 256) rpb_l[f] = rpb[h * 169 + f];
        __syncthreads();

        const __hip_bfloat16* qrow = qb + ((size_t)h * NPAD + i * 56) * 64;
        const __hip_bfloat16* kwin = kb + ((size_t)h * NPAD + ni * 56) * 64;

        for (int rt = 0; rt < 4; rt++) {
            bf16x8 af0 = *(const bf16x8*)(qrow + (size_t)(rt * 16 + l15) * 64 + l4 * 8);
            bf16x8 af1 = *(const bf16x8*)(qrow + (size_t)(rt * 16 + l15) * 64 + 32 + l4 * 8);
            for (int ct = wv; ct < 25; ct += 4) {
                bf16x8 b0 = *(const bf16x8*)(kwin + (size_t)(ct * 16 + l15) * 64 + l4 * 8);
                bf16x8 b1 = *(const bf16x8*)(kwin + (size_t)(ct * 16 + l15) * 64 + 32 + l4 * 8);
                f32x4 acc = {};
                acc = __builtin_amdgcn_mfma_f32_16x16x32_bf16(af0, b0, acc, 0, 0, 0);
                acc = __builtin_amdgcn_mfma_f32_16x16x32_bf16(af1, b1, acc, 0, 0, 0);
                int col = ct * 16 + l15;
                #pragma unroll
                for (int r = 0; r < 4; r++)
                    Sl[l4 * 4 + r][col] = acc[r];
            }
            __syncthreads();
            #pragma unroll
            for (int pp = 0; pp < 4; pp++) {
                int j = rt * 16 + wv * 4 + pp;
                if (j < 56) {
                    int n = i * 56 + j;
                    int nj = min(max(j - 3, 0), 49);
                    int t = lane;
                    float logit = -1e30f;
                    if (t < KK) {
                        int u = t / 7, v = t - (t / 7) * 7;
                        int col = u * 56 + nj + v;
                        int ri = 6 - (i - ni) + u;
                        int rj = 6 - (j - nj) + v;
                        logit = Sl[j - rt * 16][col] + rpb_l[ri * 13 + rj];
                    }
                    float m = logit;
                    #pragma unroll
                    for (int off = 32; off; off >>= 1) m = fmaxf(m, __shfl_xor(m, off));
                    float e = (t < KK) ? expf(logit - m) : 0.f;
                    float ssum = e;
                    #pragma unroll
                    for (int off = 32; off; off >>= 1) ssum += __shfl_xor(ssum, off);
                    if (t < KK) attn[(size_t)n * C2 + h * KK + t] = e / ssum;
                }
            }
            __syncthreads();
        }
    } else {
        // ----- grouped 7x7 conv + GELU (had fused, float4 staging) -----
        float (*smem)[8][68] = (float(*)[8][68])sraw;
        int cb = blockIdx.x - 448;
        int g = cb % 54;
        int rt = cb / 54;          // 0..13
        int r0 = rt * TH;
        int waveid = tid >> 6, lane = tid & 63;
        int ic = lane >> 3, oc = lane & 7;

        float* sflat = &smem[0][0][0];
        for (int i = tid; i < 10 * 8 * 68; i += 256) sflat[i] = 0.f;

        float wreg[49];
        {
            const float* wp = w + ((size_t)(g * 8 + oc) * 8 + ic) * 49;
            #pragma unroll
            for (int t = 0; t < 49; t++) wreg[t] = wp[t];
        }
        __syncthreads();

        for (int f = tid; f < 10 * 56 * 2; f += 256) {
            int rr = f / 112, rem = f - rr * 112;
            int pj = rem >> 1, half = rem & 1;
            int pi = r0 - 3 + rr;
            if (pi >= 0 && pi < 56) {
                size_t off = (size_t)(pi * 56 + pj) * CDIM + g * 8 + half * 4;
                float4 qv = *(const float4*)(q + off);
                float4 kv = *(const float4*)(k + off);
                int c0 = half * 4;
                smem[rr][c0 + 0][pj + 3] = qv.x * kv.x * scale;
                smem[rr][c0 + 1][pj + 3] = qv.y * kv.y * scale;
                smem[rr][c0 + 2][pj + 3] = qv.z * kv.z * scale;
                smem[rr][c0 + 3][pj + 3] = qv.w * kv.w * scale;
            }
        }
        __syncthreads();

        int r = r0 + waveid;
        float bias_o = b[g * 8 + oc];
        for (int j0 = 0; j0 < 56; j0 += 4) {
            float acc0 = 0.f, acc1 = 0.f, acc2 = 0.f, acc3 = 0.f;
            #pragma unroll
            for (int u = 0; u < 7; u++) {
                const float* rp = &smem[waveid + u][ic][j0];
                float4 c0 = *(const float4*)(rp);
                float4 c1 = *(const float4*)(rp + 4);
                float4 c2 = *(const float4*)(rp + 8);
                float col[12] = {c0.x, c0.y, c0.z, c0.w,
                                 c1.x, c1.y, c1.z, c1.w,
                                 c2.x, c2.y, c2.z, c2.w};
                #pragma unroll
                for (int v = 0; v < 7; v++) {
                    float wv2 = wreg[u * 7 + v];
                    acc0 += wv2 * col[v + 0];
                    acc1 += wv2 * col[v + 1];
                    acc2 += wv2 * col[v + 2];
                    acc3 += wv2 * col[v + 3];
                }
            }
            float accs[4] = {acc0, acc1, acc2, acc3};
            #pragma unroll
            for (int jj = 0; jj < 4; jj++) {
                float s = accs[jj];
                s += __shfl_xor(s, 8);
                s += __shfl_xor(s, 16);
                s += __shfl_xor(s, 32);
                accs[jj] = s;
            }
            if (ic == 0) {
                #pragma unroll
                for (int jj = 0; jj < 4; jj++) {
                    float a = accs[jj] + bias_o;
                    float gl = 0.5f * a * (1.0f + erff(a * 0.70710678118654752f));
                    int n = r * 56 + j0 + jj;
                    int kch = g * 8 + oc;
                    out[perm_off(n, kch, 448)] = __float2bfloat16(gl);
                }
            }
        }
    }
}

// ---------------------------------------------------------------------------
// softmax_pack: per pixel: softmax over 392 channels of h2, then pack per
// (head, tap): hi16 = bf16(attn), lo16 = bf16(attn + hat) into pk[n][h][52].
// ---------------------------------------------------------------------------
__global__ __launch_bounds__(128) void softmax_pack(
    const float* __restrict__ h2, const float* __restrict__ attn,
    unsigned* __restrict__ pk)
{
    __shared__ float red[128];
    int n = blockIdx.x, tid = threadIdx.x;
    const float* row = h2 + (size_t)n * C2;
    float m = -1e30f;
    float rv[4];
    #pragma unroll
    for (int idx = 0; idx < 4; idx++) {
        int c = tid + idx * 128;
        rv[idx] = (c < C2) ? row[c] : -1e30f;
        m = fmaxf(m, rv[idx]);
    }
    red[tid] = m; __syncthreads();
    for (int s = 64; s; s >>= 1) {
        if (tid < s) red[tid] = fmaxf(red[tid], red[tid + s]);
        __syncthreads();
    }
    m = red[0]; __syncthreads();
    float loc = 0.f;
    #pragma unroll
    for (int idx = 0; idx < 4; idx++) {
        int c = tid + idx * 128;
        if (c < C2) { rv[idx] = expf(rv[idx] - m); loc += rv[idx]; }
    }
    red[tid] = loc; __syncthreads();
    for (int s = 64; s; s >>= 1) {
        if (tid < s) red[tid] += red[tid + s];
        __syncthreads();
    }
    float inv = 1.0f / red[0];
    #pragma unroll
    for (int idx = 0; idx < 4; idx++) {
        int c = tid + idx * 128;
        if (c < C2) {
            float hval = rv[idx] * inv;
            float a = attn[(size_t)n * C2 + c];
            int hh = c / KK, t = c - hh * KK;
            unsigned word = ((unsigned)f2bf(a) << 16) | (unsigned)f2bf(a + hval);
            pk[((size_t)n * 8 + hh) * 52 + t] = word;
        }
    }
}

// ---------------------------------------------------------------------------
// Fused combine: blocks [0,5000) interior (one wave per pixel), blocks
// [5000,6272) border. pk wave-uniform weights (zero shfl); ghost in LDS.
// ---------------------------------------------------------------------------
__global__ __launch_bounds__(256) void combine_fused(
    const __hip_bfloat16* __restrict__ vb, const unsigned* __restrict__ pk,
    const float* __restrict__ ghostT, __hip_bfloat16* __restrict__ comb)
{
    __shared__ float gs[KK * HD];
    int tid = threadIdx.x;
    int lane = tid & 63;

    if (blockIdx.x < 5000) {
        int bid = blockIdx.x;
        int nb = (bid & 7) * 625 + (bid >> 3);    // 5000 = 8 * 625
        int h = (nb * 4) / 2500;                   // uniform per block
        for (int f = tid; f < KK * HD; f += 256) {
            int t = f / HD, dd = f - t * HD;
            gs[f] = ghostT[t * CDIM + h * HD + dd];
        }
        __syncthreads();

        int task = nb * 4 + (tid >> 6);
        task = __builtin_amdgcn_readfirstlane(task);
        int rem = task - h * 2500;
        int i = 3 + rem / 50;
        int j = 3 + (rem - (rem / 50) * 50);
        int n = i * 56 + j;
        int d = (lane < HD) ? lane : (HD - 1);
        bool lo = (d < 27);

        const unsigned* pkrow = pk + ((size_t)n * 8 + h) * 52;
        const __hip_bfloat16* vwin =
            vb + ((size_t)h * N_PIX + (i - 3) * 56 + (j - 3)) * 64 + d;

        float S_ah = 0.f, S_a = 0.f, S_g = 0.f;
        #pragma unroll
        for (int u = 0; u < 7; u++) {
            float vrow[7];
            #pragma unroll
            for (int vv = 0; vv < 7; vv++)
                vrow[vv] = __bfloat162float(vwin[(u * 56 + vv) * 64]);
            #pragma unroll
            for (int vv = 0; vv < 7; vv++) {
                const int t = u * 7 + vv;
                unsigned s = pkrow[t];
                float a  = __uint_as_float(s & 0xFFFF0000u);
                float ah = __uint_as_float(s << 16);
                float gt = gs[t * HD + d];
                S_ah += ah * vrow[vv];
                S_a  += a  * vrow[vv];
                S_g  += gt * vrow[vv];
            }
        }
        if (lane < HD) {
            float av = S_ah;
            float Sh = S_ah - S_a;
            float elsa = S_g + (lo ? S_a : Sh);
            comb[perm_off(n, h * 108 + d, 896)]      = __float2bfloat16(av);
            comb[perm_off(n, h * 108 + 54 + d, 896)] = __float2bfloat16(elsa);
        }
    } else {
        int bid = blockIdx.x - 5000;
        int nb = (bid & 7) * 159 + (bid >> 3);    // 1272 = 8 * 159
        int h = (nb * 4) / 636;                    // uniform per block
        for (int f = tid; f < KK * HD; f += 256) {
            int t = f / HD, dd = f - t * HD;
            gs[f] = ghostT[t * CDIM + h * HD + dd];
        }
        __syncthreads();

        int task = nb * 4 + (tid >> 6);
        task = __builtin_amdgcn_readfirstlane(task);
        int idx = task - h * 636;
        int i, j;
        if (idx < 336) {
            int r = idx / 56;
            i = (r < 3) ? r : 50 + r;             // 0,1,2,53,54,55
            j = idx - r * 56;
        } else {
            int idx2 = idx - 336;                 // 0..299
            i = 3 + idx2 / 6;
            int jj = idx2 - (idx2 / 6) * 6;
            j = (jj < 3) ? jj : 50 + jj;          // 0,1,2, 53,54,55
        }
        int n = i * 56 + j;
        int d = (lane < HD) ? lane : (HD - 1);
        bool lo = (d < 27);

        const unsigned* pkrow = pk + ((size_t)n * 8 + h) * 52;
        int ni = min(max(i - 3, 0), 49), nj = min(max(j - 3, 0), 49);
        const __hip_bfloat16* vhead = vb + (size_t)h * N_PIX * 64 + d;
        const __hip_bfloat16* vbc = vhead + (size_t)(ni * 56 + nj) * 64;

        float S_ahc = 0.f, S_ap = 0.f, S_ahp = 0.f, S_gp = 0.f;
        #pragma unroll
        for (int t = 0; t < KK; t++) {
            const int u = t / 7, vv = t % 7;
            unsigned s = pkrow[t];
            float a  = __uint_as_float(s & 0xFFFF0000u);
            float ah = __uint_as_float(s << 16);
            float vc = __bfloat162float(vbc[(u * 56 + vv) * 64]);
            S_ahc += ah * vc;
            int pi = i + u - 3, pj = j + vv - 3;
            if (pi >= 0 && pi < 56 && pj >= 0 && pj < 56) {
                float vp = __bfloat162float(vhead[(size_t)(pi * 56 + pj) * 64]);
                float gt = gs[t * HD + d];
                S_ahp += ah * vp; S_ap += a * vp; S_gp += gt * vp;
            }
        }
        if (lane < HD) {
            float av = S_ahc;
            float Shp = S_ahp - S_ap;
            float elsa = S_gp + (lo ? S_ap : Shp);
            comb[perm_off(n, h * 108 + d, 896)]      = __float2bfloat16(av);
            comb[perm_off(n, h * 108 + 54 + d, 896)] = __float2bfloat16(elsa);
        }
    }
}

extern "C" void kernel_launch(void* const* d_in, const int* in_sizes, int n_in,
                              void* d_out, int out_size, void* d_ws, size_t ws_size,
                              hipStream_t stream)
{
    const float* x       = (const float*)d_in[0];
    const float* qkv_w   = (const float*)d_in[1];
    const float* qkv_b   = (const float*)d_in[2];
    const float* rpb     = (const float*)d_in[3];
    const float* conv1_w = (const float*)d_in[4];
    const float* conv1_b = (const float*)d_in[5];
    const float* conv2_w = (const float*)d_in[6];
    const float* conv2_b = (const float*)d_in[7];
    const float* ghost   = (const float*)d_in[8];
    const float* proj2_w = (const float*)d_in[9];
    const float* proj2_b = (const float*)d_in[10];
    float* out = (float*)d_out;

    float* ws = (float*)d_ws;
    const size_t NC = (size_t)N_PIX * CDIM;       // 1354752
    const size_t NA = (size_t)N_PIX * C2;         // 1229312
    float* q      = ws;
    float* k      = q + NC;
    float* attn   = k + NC;
    float* hat    = attn + NA;
    float* ghostT = hat + NA;                     // 21168
    unsigned* pk  = (unsigned*)(ghostT + 21168);  // 3136*8*52 = 1304576
    __hip_bfloat16* bfbase = (__hip_bfloat16*)(pk + 1304576);
    __hip_bfloat16* xb     = bfbase;                    // 3136 x 448
    __hip_bfloat16* qkvwb  = xb    + (size_t)3136 * 448;
    __hip_bfloat16* c2wb   = qkvwb + (size_t)1344 * 448;
    __hip_bfloat16* p2wb   = c2wb  + (size_t)448 * 448;
    __hip_bfloat16* hb     = p2wb  + (size_t)448 * 896; // 3136 x 448
    __hip_bfloat16* cb     = hb    + (size_t)3136 * 448;// 3136 x 896
    __hip_bfloat16* vb16   = cb    + (size_t)3136 * 896;// 8 x 3136 x 64
    __hip_bfloat16* qb16   = vb16  + (size_t)8 * N_PIX * 64; // 8 x 3200 x 64
    __hip_bfloat16* kb16   = qb16  + (size_t)8 * NPAD * 64;  // 8 x 3200 x 64

    const float scale = 0.13608276348795434f;     // 54^-0.5

    prep_kernel<<<1557, 256, 0, stream>>>(
        x, qkv_w, conv2_w, proj2_w, ghost, xb, qkvwb, c2wb, p2wb, ghostT, qb16);

    // qkv = x @ qkv_w^T + b  -> q fp32+qb16, k fp32+kb16, v bf16 head-major
    gemm_mfma<<<dim3(21, 49), 256, 0, stream>>>(
        xb, qkvwb, qkv_b, q, k, vb16, qb16, kb16, 1296, 448, 0, scale, 0);

    // attn (MFMA) and conv1 run concurrently in one launch
    attn_conv1<<<448 + 756, 256, 0, stream>>>(
        qb16, kb16, rpb, attn, q, k, conv1_w, conv1_b, hb, scale);

    gemm_mfma<<<dim3(7, 49), 256, 0, stream>>>(
        hb, c2wb, conv2_b, hat, nullptr, nullptr, nullptr, nullptr,
        392, 448, 1, 1.f, 392);

    softmax_pack<<<N_PIX, 128, 0, stream>>>(hat, attn, pk);

    combine_fused<<<5000 + 1272, 256, 0, stream>>>(vb16, pk, ghostT, cb);

    gemm_mfma<<<dim3(7, 49), 256, 0, stream>>>(
        cb, p2wb, proj2_b, out, nullptr, nullptr, nullptr, nullptr,
        432, 896, 1, 1.f, 432);
}